// Round 7
// baseline (166.313 us; speedup 1.0000x reference)
//
#include <hip/hip_runtime.h>
#include <hip/hip_fp16.h>
#include <hip/hip_cooperative_groups.h>

namespace cg = cooperative_groups;

// DFMB PSROIAlign — fp16 row-line gathers + sorted rois, 2 dispatches.
//
// Cost model (R8-R14): main_kernel is pinned by the VMEM addresser — cost ~
// distinct 64B lines per gather instruction among the wave's 64 lanes.
// Unsorted: 64 distinct lines/instr -> main 46.3us (R9). Sorted by quantized
// (y0,x0,size): ~12-16 lines/instr -> main ~33us (R11/R12/R14 ledger).
// R14's 5-dispatch parallel sort was correct but launch gaps (~4.5us each)
// ate the gain (122us total).
//
// R15: ONE cooperative pre-kernel (64 blocks x 1024 thr, co-resident,
// 3 grid.sync()) fuses: {zero cursor || fp16 row-line pack} -> sync ->
// {key+hist} -> sync -> {block-0 scan, 16384 contiguous words} -> sync ->
// {scatter -> perm}. All phases verbatim from the R14-verified kernels.
// Host falls back to the R14 multi-kernel path if cooperative launch fails.
// main_kernel: byte-identical to thrice-verified version + clamp on perm
// reads (safety against a silently-failed presort; in-bounds wrong results
// instead of OOB writes).
//
// Row-line layout (R10): 3 phase copies of 64B lines; copy m line g = pixels
// [3g+m..3g+m+2] x 10ch fp16 (60B)+pad. Window at pixel fp = ONE line
// (m=fp%3, g=fp/3). Column clamp merged into element weights (linearity).

#define NC 10
#define NBIN 49
#define FH 34
#define FW 34
#define PLANE (FH * FW)
#define NPIX (NBIN * PLANE)  // 56644
#define GPC 18882            // row-lines per phase copy
#define RPB 16               // rois per block
#define TSTRIDE 491          // out-tile row stride (odd -> conflict-free flush)
#define NSIDE 14
#define NXCD 8
#define PREP_BLOCKS 56       // ceil((NPIX+2)/1024), fallback path
#define KBUCKET 16384        // 14-bit key: y0(5) x0(5) bh(2) bw(2)
#define COOP_BLOCKS 64

// deterministic bucketing key: y0,x0 integer start; bh,bw size quartiles
__device__ __forceinline__ unsigned int roi_key(const float* __restrict__ rois, int n)
{
    const float rsw = rois[n * 5 + 1] * 0.125f;
    const float rsh = rois[n * 5 + 2] * 0.125f;
    const float rew = rois[n * 5 + 3] * 0.125f;
    const float reh = rois[n * 5 + 4] * 0.125f;
    float rh = reh - rsh; if (!(rh > 0.1f)) rh = 0.1f;
    float rw = rew - rsw; if (!(rw > 0.1f)) rw = 0.1f;
    const int y0 = min(31, max(0, (int)floorf(rsh)));
    const int x0 = min(31, max(0, (int)floorf(rsw)));
    const int bh = min(3, (int)(rh * (4.0f / 9.0f)));  // rheight in (0.1,9]
    const int bw = min(3, (int)(rw * (4.0f / 9.0f)));
    return (unsigned int)(((((y0 << 5) | x0) << 2 | bh) << 2) | bw);
}

__device__ __forceinline__ void pack_pixel(
    const float* __restrict__ ft, unsigned int* __restrict__ ftR, int p)
{
    unsigned int h2[5];
    if (p < NPIX) {
#pragma unroll
        for (int c = 0; c < 5; ++c) {
            const __half lo = __float2half_rn(ft[(2 * c)     * NPIX + p]);
            const __half hi = __float2half_rn(ft[(2 * c + 1) * NPIX + p]);
            const __half2 hh = __halves2half2(lo, hi);
            h2[c] = *(const unsigned int*)&hh;
        }
    } else {
#pragma unroll
        for (int c = 0; c < 5; ++c) h2[c] = 0u;  // tail: finite zeros
    }
    // pixel p -> copy m (m<=p), line g=(p-m)/3, slot j=(p-m)%3
#pragma unroll
    for (int m = 0; m < 3; ++m) {
        if (p >= m) {
            const int t = p - m;
            const int g = t / 3;
            const int j = t - 3 * g;
            if (g < GPC) {
                unsigned int* d = ftR + ((size_t)m * GPC + g) * 16 + j * 5;
#pragma unroll
                for (int c = 0; c < 5; ++c) d[c] = h2[c];
            }
        }
    }
}

// ---- fused cooperative presort: zero+pack -> hist -> scan -> scatter ----
__global__ __launch_bounds__(1024) void presort_kernel(
    const float* __restrict__ ft, unsigned int* __restrict__ ftR,
    const float* __restrict__ rois, unsigned int* __restrict__ keys,
    unsigned int* __restrict__ cursor, int* __restrict__ perm, int N)
{
    __shared__ unsigned int part[1024];
    cg::grid_group grid = cg::this_grid();
    const int tid = blockIdx.x * 1024 + threadIdx.x;
    const int nthr = COOP_BLOCKS * 1024;

    // phase 1: zero cursor (cursor only) || pack ftR (ftR only)
    for (int i = tid; i < KBUCKET; i += nthr) cursor[i] = 0u;
    for (int p = tid; p < NPIX + 2; p += nthr) pack_pixel(ft, ftR, p);
    grid.sync();

    // phase 2: keys + histogram
    for (int n = tid; n < N; n += nthr) {
        const unsigned int k = roi_key(rois, n);
        keys[n] = k;
        atomicAdd(&cursor[k], 1u);
    }
    grid.sync();

    // phase 3: exclusive scan (block 0; contiguous 16 words/thread)
    if (blockIdx.x == 0) {
        const int t = threadIdx.x;
        unsigned int c[16];     // static-indexed -> registers (rule #20)
        unsigned int s = 0;
#pragma unroll
        for (int i = 0; i < 16; ++i) { c[i] = cursor[t * 16 + i]; s += c[i]; }
        part[t] = s;
        __syncthreads();
        for (int off = 1; off < 1024; off <<= 1) {
            const unsigned int v = (t >= off) ? part[t - off] : 0u;
            __syncthreads();
            part[t] += v;
            __syncthreads();
        }
        unsigned int base = (t == 0) ? 0u : part[t - 1];
#pragma unroll
        for (int i = 0; i < 16; ++i) { cursor[t * 16 + i] = base; base += c[i]; }
    }
    grid.sync();

    // phase 4: scatter
    for (int n = tid; n < N; n += nthr) {
        const unsigned int pos = atomicAdd(&cursor[keys[n]], 1u);
        if (pos < (unsigned int)N) perm[pos] = n;
    }
}

// ---- fallback (R14-verified) multi-kernel sort path ----
__global__ __launch_bounds__(1024) void zero_kernel(unsigned int* __restrict__ cursor)
{
    cursor[blockIdx.x * 1024 + threadIdx.x] = 0u;
}

__global__ __launch_bounds__(1024) void prep_hist_kernel(
    const float* __restrict__ ft, unsigned int* __restrict__ ftR,
    const float* __restrict__ rois, unsigned int* __restrict__ keys,
    unsigned int* __restrict__ cursor, int N)
{
    if (blockIdx.x >= PREP_BLOCKS) {
        const int n = (blockIdx.x - PREP_BLOCKS) * 1024 + threadIdx.x;
        if (n < N) {
            const unsigned int k = roi_key(rois, n);
            keys[n] = k;
            atomicAdd(&cursor[k], 1u);
        }
        return;
    }
    const int p = blockIdx.x * 1024 + threadIdx.x;
    if (p < NPIX + 2) pack_pixel(ft, ftR, p);
}

__global__ __launch_bounds__(1024) void scan_kernel(unsigned int* __restrict__ cursor)
{
    __shared__ unsigned int part[1024];
    const int t = threadIdx.x;
    unsigned int c[16];
    unsigned int s = 0;
#pragma unroll
    for (int i = 0; i < 16; ++i) { c[i] = cursor[t * 16 + i]; s += c[i]; }
    part[t] = s;
    __syncthreads();
    for (int off = 1; off < 1024; off <<= 1) {
        const unsigned int v = (t >= off) ? part[t - off] : 0u;
        __syncthreads();
        part[t] += v;
        __syncthreads();
    }
    unsigned int base = (t == 0) ? 0u : part[t - 1];
#pragma unroll
    for (int i = 0; i < 16; ++i) { cursor[t * 16 + i] = base; base += c[i]; }
}

__global__ __launch_bounds__(1024) void scatter_kernel(
    const unsigned int* __restrict__ keys, unsigned int* __restrict__ cursor,
    int* __restrict__ perm, int N)
{
    const int n = blockIdx.x * 1024 + threadIdx.x;
    if (n >= N) return;
    const unsigned int pos = atomicAdd(&cursor[keys[n]], 1u);
    if (pos < (unsigned int)N) perm[pos] = n;
}

__device__ __forceinline__ void fma2(float w, unsigned int u, float& s0, float& s1)
{
    const __half2 h = *(const __half2*)&u;
    s0 = fmaf(w, __half2float(__low2half(h)),  s0);   // -> v_fma_mix_f32
    s1 = fmaf(w, __half2float(__high2half(h)), s1);
}

__global__ __launch_bounds__(256, 4) void main_kernel(
    const float* __restrict__ rois, const unsigned int* __restrict__ ftR,
    const int* __restrict__ perm, const float* __restrict__ ft,
    float* __restrict__ out, int N, int use_t)
{
    __shared__ float sides[NSIDE][RPB][8];  // 7 KB
    __shared__ float tile[RPB][TSTRIDE];    // 31.4 KB

    // XCD-chunked swizzle (bijective): sorted order -> contiguous y-band/XCD
    const int nwg = gridDim.x;
    const int q = nwg / NXCD, rr = nwg % NXCD;
    const int xcd = blockIdx.x % NXCD, idx = blockIdx.x / NXCD;
    const int bid = (xcd < rr ? xcd * (q + 1) : rr * (q + 1) + (xcd - rr) * q) + idx;

    const int r = threadIdx.x & (RPB - 1);  // roi slot within block
    const int s = threadIdx.x >> 4;         // slot 0..15
    const int n = bid * RPB + r;
    const bool valid = (n < N);
    // clamp: if presort failed, stay in-bounds (wrong-but-visible, not OOB)
    const int nn = (use_t && valid) ? min(max(perm[n], 0), N - 1) : n;

    float rsw = 0.f, rsh = 0.f, rew = 0.f, reh = 0.f;
    if (valid) {
        rsw = rois[nn * 5 + 1] * 0.125f;  // /STRIDE(8), exact pow2
        rsh = rois[nn * 5 + 2] * 0.125f;
        rew = rois[nn * 5 + 3] * 0.125f;
        reh = rois[nn * 5 + 4] * 0.125f;
    }
    // Explicit _rn chain: floor/ceil/compare inputs must bit-match numpy fp32.
    float rheight = __fsub_rn(reh, rsh);
    if (!(rheight > 0.1f)) rheight = 0.1f;
    float rwidth = __fsub_rn(rew, rsw);
    if (!(rwidth > 0.1f)) rwidth = 0.1f;
    const float bsh   = __fdiv_rn(rheight, 7.0f);
    const float bsw   = __fdiv_rn(rwidth, 7.0f);
    const float sub_h = __fdiv_rn(bsh, 4.0f);
    const float sub_w = __fdiv_rn(bsw, 4.0f);

    // ---- phase 1: one axis-side per slot (slots 0..13 active) ----
    if (s < NSIDE) {
        const bool isY = (s < 7);
        const int  k   = isY ? s : s - 7;
        const float st = isY ? rsh : rsw;
        const float bs = isY ? bsh : bsw;
        const float sb = isY ? sub_h : sub_w;
        const float start = floorf(__fadd_rn(st, __fmul_rn((float)k, bs)));

        float A[3] = {0.f, 0.f, 0.f}, B[3] = {0.f, 0.f, 0.f};
        float cnt = 0.f;
        int P0 = 0;
#pragma unroll
        for (int i = 0; i < 4; ++i) {
            const float h = __fadd_rn(start, __fmul_rn((float)i + 0.5f, sb));
            const bool ok = (h > -1.0f) && (h < 34.0f);
            const int p1 = (int)floorf(h);
            const int p2 = (int)ceilf(h);
            const bool v1 = (p1 >= 0) && (p1 < 34);
            const bool v2 = (p2 >= 0) && (p2 < 34);
            const int p1c = min(max(p1, 0), 33);
            const int p2c = min(max(p2, 0), 33);
            const float d = __fsub_rn(h, (float)p1c);  // vs CLIPPED corner
            if (i == 0) P0 = p1c;                      // min (h increasing)
            const int i1 = p1c - P0, i2 = p2c - P0;    // in {0,1,2}
            const float t1 = ok ? (1.0f - d) : 0.0f;
            const float t2 = ok ? d : 0.0f;
            // bad11 = (!x1v || !x2v) && (y1v || y2v): X carries "invalid",
            // Y carries "valid".
            const bool bsel = isY ? (v1 || v2) : ((!v1) || (!v2));
            const float tb = (ok && bsel) ? (1.0f - d) : 0.0f;
            cnt += ok ? 1.0f : 0.0f;
#pragma unroll
            for (int p = 0; p < 3; ++p) {
                A[p] += (i1 == p) ? t1 : 0.0f;
                A[p] += (i2 == p) ? t2 : 0.0f;
                B[p] += (i1 == p) ? tb : 0.0f;
            }
        }
        float* sp = &sides[s][r][0];
        sp[0] = A[0]; sp[1] = A[1]; sp[2] = A[2];
        sp[3] = B[0]; sp[4] = B[1]; sp[5] = B[2];
        sp[6] = cnt;  sp[7] = (float)P0;
    }
    __syncthreads();

    // ---- phase 2: 4 bins/thread; 3 row-lines per bin ----
#pragma unroll
    for (int j = 0; j < 4; ++j) {
        const int bin = j * RPB + s;
        if (valid && bin < NBIN) {
            const int ph = bin / 7;
            const int pw = bin - ph * 7;

            const float4 ya = *(const float4*)&sides[ph][r][0];
            const float4 yb = *(const float4*)&sides[ph][r][4];
            const float4 xa = *(const float4*)&sides[7 + pw][r][0];
            const float4 xb = *(const float4*)&sides[7 + pw][r][4];
            const float AY[3] = {ya.x, ya.y, ya.z};
            const float BY[3] = {ya.w, yb.x, yb.y};
            const float cntY  = yb.z;
            const int   Y0    = (int)yb.w;
            const float AX[3] = {xa.x, xa.y, xa.z};
            const float BX[3] = {xa.w, xb.x, xb.y};
            const float cntX  = xb.z;
            const int   X0    = (int)xb.w;

            const int binbase = bin * PLANE;
            const int rowo[3] = {binbase + Y0 * FW,
                                 binbase + min(Y0 + 1, FH - 1) * FW,
                                 binbase + min(Y0 + 2, FH - 1) * FW};

            float wgt[9];
#pragma unroll
            for (int p = 0; p < 3; ++p)
#pragma unroll
                for (int q2 = 0; q2 < 3; ++q2)
                    wgt[3 * p + q2] = AY[p] * AX[q2] - BY[p] * BX[q2];

            float sum[NC];
#pragma unroll
            for (int c = 0; c < NC; ++c) sum[c] = 0.f;

            if (use_t) {
                const int e = (FW - 1) - X0;  // >= 0; clamp width of row window
                unsigned int rv[3][15];
                float ew[3][3];
#pragma unroll
                for (int p = 0; p < 3; ++p) {
                    const float w0 = wgt[3 * p], w1 = wgt[3 * p + 1], w2 = wgt[3 * p + 2];
                    const float s12 = w1 + w2;
                    ew[p][0] = (e < 1) ? (w0 + s12) : w0;
                    ew[p][1] = (e < 1) ? 0.f : ((e < 2) ? s12 : w1);
                    ew[p][2] = (e < 2) ? 0.f : w2;
                    const bool rnz = (w0 != 0.0f) || (w1 != 0.0f) || (w2 != 0.0f);
                    const int fp = rnz ? (rowo[p] + X0) : binbase;
                    const int g = fp / 3;
                    const int m = fp - 3 * g;
                    const unsigned int* lp = ftR + ((size_t)m * GPC + g) * 16;
                    const uint4 a = *(const uint4*)lp;
                    const uint4 b = *(const uint4*)(lp + 4);
                    const uint4 c4 = *(const uint4*)(lp + 8);
                    const uint4 d4 = *(const uint4*)(lp + 12);
                    rv[p][0]  = a.x;  rv[p][1]  = a.y;  rv[p][2]  = a.z;  rv[p][3]  = a.w;
                    rv[p][4]  = b.x;  rv[p][5]  = b.y;  rv[p][6]  = b.z;  rv[p][7]  = b.w;
                    rv[p][8]  = c4.x; rv[p][9]  = c4.y; rv[p][10] = c4.z; rv[p][11] = c4.w;
                    rv[p][12] = d4.x; rv[p][13] = d4.y; rv[p][14] = d4.z;  // d4.w = pad
                }
#pragma unroll
                for (int p = 0; p < 3; ++p)
#pragma unroll
                    for (int c = 0; c < 5; ++c) {
                        fma2(ew[p][0], rv[p][c],      sum[2 * c], sum[2 * c + 1]);
                        fma2(ew[p][1], rv[p][5 + c],  sum[2 * c], sum[2 * c + 1]);
                        fma2(ew[p][2], rv[p][10 + c], sum[2 * c], sum[2 * c + 1]);
                    }
            } else {
                const int colo[3] = {X0, min(X0 + 1, FW - 1), min(X0 + 2, FW - 1)};
                int off[9];
#pragma unroll
                for (int p = 0; p < 3; ++p)
#pragma unroll
                    for (int q2 = 0; q2 < 3; ++q2)
                        off[3 * p + q2] = (wgt[3 * p + q2] != 0.0f) ? (rowo[p] + colo[q2])
                                                                    : binbase;
#pragma unroll
                for (int k = 0; k < 9; ++k) {
                    const float w = wgt[k];
#pragma unroll
                    for (int c = 0; c < NC; ++c)
                        sum[c] = fmaf(w, ft[c * NPIX + off[k]], sum[c]);
                }
            }

            const float cnt = cntY * cntX;
            const float inv = (cnt > 0.0f) ? __fdiv_rn(1.0f, cnt) : 1.0f;
            float* tp = &tile[r][0];
#pragma unroll
            for (int c = 0; c < NC; ++c) tp[c * NBIN + bin] = sum[c] * inv;
        }
    }

    __syncthreads();

    // Coalesced flush: 16 rois x 490 contiguous floats, scattered by perm.
    const int n0 = bid * RPB;
    for (int i = threadIdx.x; i < RPB * (NC * NBIN); i += 256) {
        const int row = i / (NC * NBIN);
        const int col = i - row * (NC * NBIN);
        const int n2 = n0 + row;
        if (n2 < N) {
            const int nd = use_t ? min(max(perm[n2], 0), N - 1) : n2;
            out[(size_t)nd * (NC * NBIN) + col] = tile[row][col];
        }
    }
}

extern "C" void kernel_launch(void* const* d_in, const int* in_sizes, int n_in,
                              void* d_out, int out_size, void* d_ws, size_t ws_size,
                              hipStream_t stream) {
    const float* ft   = (const float*)d_in[0];
    const float* rois = (const float*)d_in[1];
    float* out        = (float*)d_out;
    const int N = in_sizes[1] / 5;

    // ws layout: ftR (3 x GPC x 64B = 3,625,344 B) | cursor (64KB) | keys | perm
    const size_t ftr_bytes = (size_t)3 * GPC * 64;
    const size_t need = ftr_bytes + (size_t)KBUCKET * 4 + (size_t)8 * N;
    const int use_t = (ws_size >= need) ? 1 : 0;
    unsigned int* ftR    = (unsigned int*)d_ws;
    unsigned int* cursor = (unsigned int*)((char*)d_ws + ftr_bytes);
    unsigned int* keys   = cursor + KBUCKET;
    int*          perm   = (int*)(keys + N);

    if (use_t) {
        // try fused cooperative presort (1 dispatch); fall back to R14 path
        int Nv = N;
        void* args[] = {(void*)&ft, (void*)&ftR, (void*)&rois, (void*)&keys,
                        (void*)&cursor, (void*)&perm, (void*)&Nv};
        hipError_t err = hipLaunchCooperativeKernel(
            (const void*)presort_kernel, dim3(COOP_BLOCKS), dim3(1024),
            args, 0, stream);
        if (err != hipSuccess) {
            const int hb = (N + 1023) / 1024;
            zero_kernel<<<KBUCKET / 1024, 1024, 0, stream>>>(cursor);
            prep_hist_kernel<<<PREP_BLOCKS + hb, 1024, 0, stream>>>(
                ft, ftR, rois, keys, cursor, N);
            scan_kernel<<<1, 1024, 0, stream>>>(cursor);
            scatter_kernel<<<hb, 1024, 0, stream>>>(keys, cursor, perm, N);
        }
    }
    main_kernel<<<(N + RPB - 1) / RPB, 256, 0, stream>>>(rois, ftR, perm, ft, out, N, use_t);
}

// Round 8
// 114.328 us; speedup vs baseline: 1.4547x; 1.4547x over previous
//
#include <hip/hip_runtime.h>
#include <hip/hip_fp16.h>

// DFMB PSROIAlign — fp16 row-line gathers + software-pipelined main.
//
// Model re-fit (R8-R15): main = base(~40us) + 0.5us x gather-instr. The
// instr/line term chased in R9-R15 is only ~6us of 46; sorting cut main to
// ~33 but every delivery mechanism (4-kernel, 1-block LDS, 5-kernel parallel,
// cooperative) cost >= its gain in launch/serialization overhead. CLOSED.
//
// The base: VALU work is ~19us (matches VALUBusy 40% x 46us); the other
// ~26us is UNHIDDEN L2 latency — each bin's 12 gathers (~300cyc) are issued
// and immediately consumed; ~2.4 waves/SIMD can't cover it, and the
// `if (valid && bin<NBIN)` branch between j-iterations blocks compiler
// hoisting of bin j+1 loads above bin j FMAs.
//
// R16: keep R9's 2-dispatch host path (prep + main, no sort). Phase 2 is a
// branchless explicit depth-1 pipeline with named A/B register buffers
// (static indexing, rule #20): meta(j+1); load(j+1); fma(j). Invalid bins
// (j=3, s>0) get ew=0 / fp=0 (shared hot line 0) and a guarded store —
// sides reads for bin>=49 stay in-bounds (ph<=9 < NSIDE=14, values finite).
// __launch_bounds__(256,3) caps VGPR (~145 est) to avoid spill.
//
// Row-line layout (R10, verified R10-R15): 3 phase copies of 64B lines;
// copy m line g = pixels [3g+m..3g+m+2] x 10ch fp16 (60B)+pad. Window at
// pixel fp = ONE line (m=fp%3, g=fp/3). Column clamp merged into element
// weights (linearity). NaN safety: prep writes every readable slot incl.
// 2 zero tail pixels; ew=0 lanes read real finite data (line 0 / binbase).

#define NC 10
#define NBIN 49
#define FH 34
#define FW 34
#define PLANE (FH * FW)
#define NPIX (NBIN * PLANE)  // 56644
#define GPC 18882            // row-lines per phase copy
#define RPB 16               // rois per block
#define TSTRIDE 491          // out-tile row stride (odd -> conflict-free flush)
#define NSIDE 14

__device__ __forceinline__ void pack_pixel(
    const float* __restrict__ ft, unsigned int* __restrict__ ftR, int p)
{
    unsigned int h2[5];
    if (p < NPIX) {
#pragma unroll
        for (int c = 0; c < 5; ++c) {
            const __half lo = __float2half_rn(ft[(2 * c)     * NPIX + p]);
            const __half hi = __float2half_rn(ft[(2 * c + 1) * NPIX + p]);
            const __half2 hh = __halves2half2(lo, hi);
            h2[c] = *(const unsigned int*)&hh;
        }
    } else {
#pragma unroll
        for (int c = 0; c < 5; ++c) h2[c] = 0u;  // tail: finite zeros
    }
    // pixel p -> copy m (m<=p), line g=(p-m)/3, slot j=(p-m)%3
#pragma unroll
    for (int m = 0; m < 3; ++m) {
        if (p >= m) {
            const int t = p - m;
            const int g = t / 3;
            const int j = t - 3 * g;
            if (g < GPC) {
                unsigned int* d = ftR + ((size_t)m * GPC + g) * 16 + j * 5;
#pragma unroll
                for (int c = 0; c < 5; ++c) d[c] = h2[c];
            }
        }
    }
}

__global__ __launch_bounds__(1024) void prep_kernel(
    const float* __restrict__ ft, unsigned int* __restrict__ ftR)
{
    const int p = blockIdx.x * 1024 + threadIdx.x;
    if (p < NPIX + 2) pack_pixel(ft, ftR, p);
}

__device__ __forceinline__ void fma2(float w, unsigned int u, float& s0, float& s1)
{
    const __half2 h = *(const __half2*)&u;
    s0 = fmaf(w, __half2float(__low2half(h)),  s0);   // -> v_fma_mix_f32
    s1 = fmaf(w, __half2float(__high2half(h)), s1);
}

// ---- phase-2 pipeline macros (all array indices static after unroll) ----

// metadata for bin (J*RPB+s): element weights EW[3][3] (column-clamp merged,
// zeroed when bin invalid), row line-start pixels FP[3] (0 when invalid,
// binbase dummy for zero-weight rows), INV = 1/count, store guard BVV.
#define BIN_META(J, EW, FP, INV, BINV, BVV)                                    \
    {                                                                          \
        BINV = (J) * RPB + s;                                                  \
        BVV = valid && (BINV < NBIN);                                          \
        const float msk = BVV ? 1.0f : 0.0f;                                   \
        const int ph = BINV / 7;                                               \
        const int pw = BINV - ph * 7;                                          \
        const float4 ya = *(const float4*)&sides[ph][r][0];                    \
        const float4 yb = *(const float4*)&sides[ph][r][4];                    \
        const float4 xa = *(const float4*)&sides[7 + pw][r][0];                \
        const float4 xb = *(const float4*)&sides[7 + pw][r][4];                \
        const float AY[3] = {ya.x, ya.y, ya.z};                                \
        const float BY[3] = {ya.w, yb.x, yb.y};                                \
        const float AX[3] = {xa.x, xa.y, xa.z};                                \
        const float BX[3] = {xa.w, xb.x, xb.y};                                \
        const int Y0 = (int)yb.w;                                              \
        const int X0 = (int)xb.w;                                              \
        const float cnt = yb.z * xb.z;                                         \
        INV = (cnt > 0.0f) ? __fdiv_rn(1.0f, cnt) : 1.0f;                      \
        const int binbase = BINV * PLANE;                                      \
        const int rowo[3] = {binbase + Y0 * FW,                                \
                             binbase + min(Y0 + 1, FH - 1) * FW,               \
                             binbase + min(Y0 + 2, FH - 1) * FW};              \
        const int e = (FW - 1) - X0;                                           \
        _Pragma("unroll") for (int p = 0; p < 3; ++p) {                        \
            const float w0 = (AY[p] * AX[0] - BY[p] * BX[0]) * msk;            \
            const float w1 = (AY[p] * AX[1] - BY[p] * BX[1]) * msk;            \
            const float w2 = (AY[p] * AX[2] - BY[p] * BX[2]) * msk;            \
            const float s12 = w1 + w2;                                         \
            EW[p][0] = (e < 1) ? (w0 + s12) : w0;                              \
            EW[p][1] = (e < 1) ? 0.f : ((e < 2) ? s12 : w1);                   \
            EW[p][2] = (e < 2) ? 0.f : w2;                                     \
            const bool rnz = (w0 != 0.0f) || (w1 != 0.0f) || (w2 != 0.0f);     \
            FP[p] = BVV ? (rnz ? (rowo[p] + X0) : binbase) : 0;                \
        }                                                                      \
    }

// gather 3 row-lines (1 64B line each; 4 x b128)
#define LOAD3(FP, RV)                                                          \
    _Pragma("unroll") for (int p = 0; p < 3; ++p) {                            \
        const int g = FP[p] / 3;                                               \
        const int m = FP[p] - 3 * g;                                           \
        const unsigned int* lp = ftR + ((size_t)m * GPC + g) * 16;             \
        const uint4 a = *(const uint4*)lp;                                     \
        const uint4 b4 = *(const uint4*)(lp + 4);                              \
        const uint4 c4 = *(const uint4*)(lp + 8);                              \
        const uint4 d4 = *(const uint4*)(lp + 12);                             \
        RV[p][0] = a.x;  RV[p][1] = a.y;  RV[p][2] = a.z;  RV[p][3] = a.w;     \
        RV[p][4] = b4.x; RV[p][5] = b4.y; RV[p][6] = b4.z; RV[p][7] = b4.w;    \
        RV[p][8] = c4.x; RV[p][9] = c4.y; RV[p][10] = c4.z; RV[p][11] = c4.w;  \
        RV[p][12] = d4.x; RV[p][13] = d4.y; RV[p][14] = d4.z; /* d4.w pad */   \
    }

#define FMA_STORE(EW, RV, INV, BINV, BVV)                                      \
    {                                                                          \
        float sum[NC];                                                         \
        _Pragma("unroll") for (int c = 0; c < NC; ++c) sum[c] = 0.f;           \
        _Pragma("unroll") for (int p = 0; p < 3; ++p)                          \
            _Pragma("unroll") for (int c = 0; c < 5; ++c) {                    \
                fma2(EW[p][0], RV[p][c],      sum[2 * c], sum[2 * c + 1]);     \
                fma2(EW[p][1], RV[p][5 + c],  sum[2 * c], sum[2 * c + 1]);     \
                fma2(EW[p][2], RV[p][10 + c], sum[2 * c], sum[2 * c + 1]);     \
            }                                                                  \
        if (BVV) {                                                             \
            float* tp = &tile[r][0];                                           \
            _Pragma("unroll") for (int c = 0; c < NC; ++c)                     \
                tp[c * NBIN + BINV] = sum[c] * INV;                            \
        }                                                                      \
    }

__global__ __launch_bounds__(256, 3) void main_kernel(
    const float* __restrict__ rois, const unsigned int* __restrict__ ftR,
    const float* __restrict__ ft, float* __restrict__ out, int N, int use_t)
{
    __shared__ float sides[NSIDE][RPB][8];  // 7 KB
    __shared__ float tile[RPB][TSTRIDE];    // 31.4 KB

    const int r = threadIdx.x & (RPB - 1);  // roi within block
    const int s = threadIdx.x >> 4;         // slot 0..15
    const int n = blockIdx.x * RPB + r;
    const bool valid = (n < N);

    float rsw = 0.f, rsh = 0.f, rew = 0.f, reh = 0.f;
    if (valid) {
        rsw = rois[n * 5 + 1] * 0.125f;  // /STRIDE(8), exact pow2
        rsh = rois[n * 5 + 2] * 0.125f;
        rew = rois[n * 5 + 3] * 0.125f;
        reh = rois[n * 5 + 4] * 0.125f;
    }
    // Explicit _rn chain: floor/ceil/compare inputs must bit-match numpy fp32.
    float rheight = __fsub_rn(reh, rsh);
    if (!(rheight > 0.1f)) rheight = 0.1f;
    float rwidth = __fsub_rn(rew, rsw);
    if (!(rwidth > 0.1f)) rwidth = 0.1f;
    const float bsh   = __fdiv_rn(rheight, 7.0f);
    const float bsw   = __fdiv_rn(rwidth, 7.0f);
    const float sub_h = __fdiv_rn(bsh, 4.0f);
    const float sub_w = __fdiv_rn(bsw, 4.0f);

    // ---- phase 1: one axis-side per slot (slots 0..13 active) ----
    if (s < NSIDE) {
        const bool isY = (s < 7);
        const int  k   = isY ? s : s - 7;
        const float st = isY ? rsh : rsw;
        const float bs = isY ? bsh : bsw;
        const float sb = isY ? sub_h : sub_w;
        const float start = floorf(__fadd_rn(st, __fmul_rn((float)k, bs)));

        float A[3] = {0.f, 0.f, 0.f}, B[3] = {0.f, 0.f, 0.f};
        float cnt = 0.f;
        int P0 = 0;
#pragma unroll
        for (int i = 0; i < 4; ++i) {
            const float h = __fadd_rn(start, __fmul_rn((float)i + 0.5f, sb));
            const bool ok = (h > -1.0f) && (h < 34.0f);
            const int p1 = (int)floorf(h);
            const int p2 = (int)ceilf(h);
            const bool v1 = (p1 >= 0) && (p1 < 34);
            const bool v2 = (p2 >= 0) && (p2 < 34);
            const int p1c = min(max(p1, 0), 33);
            const int p2c = min(max(p2, 0), 33);
            const float d = __fsub_rn(h, (float)p1c);  // vs CLIPPED corner
            if (i == 0) P0 = p1c;                      // min (h increasing)
            const int i1 = p1c - P0, i2 = p2c - P0;    // in {0,1,2}
            const float t1 = ok ? (1.0f - d) : 0.0f;
            const float t2 = ok ? d : 0.0f;
            // bad11 = (!x1v || !x2v) && (y1v || y2v): X carries "invalid",
            // Y carries "valid".
            const bool bsel = isY ? (v1 || v2) : ((!v1) || (!v2));
            const float tb = (ok && bsel) ? (1.0f - d) : 0.0f;
            cnt += ok ? 1.0f : 0.0f;
#pragma unroll
            for (int p = 0; p < 3; ++p) {
                A[p] += (i1 == p) ? t1 : 0.0f;
                A[p] += (i2 == p) ? t2 : 0.0f;
                B[p] += (i1 == p) ? tb : 0.0f;
            }
        }
        float* sp = &sides[s][r][0];
        sp[0] = A[0]; sp[1] = A[1]; sp[2] = A[2];
        sp[3] = B[0]; sp[4] = B[1]; sp[5] = B[2];
        sp[6] = cnt;  sp[7] = (float)P0;
    }
    __syncthreads();

    // ---- phase 2 ----
    if (use_t) {
        // explicit depth-1 software pipeline: load(j+1) issues before fma(j)
        float ewA[3][3], ewB[3][3];
        int   fpA[3], fpB[3];
        float invA, invB;
        int   binA, binB;
        bool  bvA, bvB;
        unsigned int rvA[3][15], rvB[3][15];

        BIN_META(0, ewA, fpA, invA, binA, bvA);
        LOAD3(fpA, rvA);
        BIN_META(1, ewB, fpB, invB, binB, bvB);
        LOAD3(fpB, rvB);
        FMA_STORE(ewA, rvA, invA, binA, bvA);
        BIN_META(2, ewA, fpA, invA, binA, bvA);
        LOAD3(fpA, rvA);
        FMA_STORE(ewB, rvB, invB, binB, bvB);
        BIN_META(3, ewB, fpB, invB, binB, bvB);
        LOAD3(fpB, rvB);
        FMA_STORE(ewA, rvA, invA, binA, bvA);
        FMA_STORE(ewB, rvB, invB, binB, bvB);
    } else {
        // fallback: direct fp32 gathers from ft
#pragma unroll
        for (int j = 0; j < 4; ++j) {
            const int bin = j * RPB + s;
            if (valid && bin < NBIN) {
                const int ph = bin / 7;
                const int pw = bin - ph * 7;
                const float4 ya = *(const float4*)&sides[ph][r][0];
                const float4 yb = *(const float4*)&sides[ph][r][4];
                const float4 xa = *(const float4*)&sides[7 + pw][r][0];
                const float4 xb = *(const float4*)&sides[7 + pw][r][4];
                const float AY[3] = {ya.x, ya.y, ya.z};
                const float BY[3] = {ya.w, yb.x, yb.y};
                const float AX[3] = {xa.x, xa.y, xa.z};
                const float BX[3] = {xa.w, xb.x, xb.y};
                const int Y0 = (int)yb.w, X0 = (int)xb.w;
                const float cnt = yb.z * xb.z;
                const int binbase = bin * PLANE;
                const int rowo[3] = {binbase + Y0 * FW,
                                     binbase + min(Y0 + 1, FH - 1) * FW,
                                     binbase + min(Y0 + 2, FH - 1) * FW};
                const int colo[3] = {X0, min(X0 + 1, FW - 1), min(X0 + 2, FW - 1)};
                float wgt[9];
                int off[9];
#pragma unroll
                for (int p = 0; p < 3; ++p)
#pragma unroll
                    for (int q2 = 0; q2 < 3; ++q2) {
                        const float w = AY[p] * AX[q2] - BY[p] * BX[q2];
                        wgt[3 * p + q2] = w;
                        off[3 * p + q2] = (w != 0.0f) ? (rowo[p] + colo[q2]) : binbase;
                    }
                float sum[NC];
#pragma unroll
                for (int c = 0; c < NC; ++c) sum[c] = 0.f;
#pragma unroll
                for (int k = 0; k < 9; ++k) {
                    const float w = wgt[k];
#pragma unroll
                    for (int c = 0; c < NC; ++c)
                        sum[c] = fmaf(w, ft[c * NPIX + off[k]], sum[c]);
                }
                const float inv = (cnt > 0.0f) ? __fdiv_rn(1.0f, cnt) : 1.0f;
                float* tp = &tile[r][0];
#pragma unroll
                for (int c = 0; c < NC; ++c) tp[c * NBIN + bin] = sum[c] * inv;
            }
        }
    }

    __syncthreads();

    // Coalesced flush: 16 rois x 490 contiguous floats each.
    const int n0 = blockIdx.x * RPB;
    for (int i = threadIdx.x; i < RPB * (NC * NBIN); i += 256) {
        const int row = i / (NC * NBIN);
        const int col = i - row * (NC * NBIN);
        const int n2 = n0 + row;
        if (n2 < N) out[(size_t)n2 * (NC * NBIN) + col] = tile[row][col];
    }
}

extern "C" void kernel_launch(void* const* d_in, const int* in_sizes, int n_in,
                              void* d_out, int out_size, void* d_ws, size_t ws_size,
                              hipStream_t stream) {
    const float* ft   = (const float*)d_in[0];
    const float* rois = (const float*)d_in[1];
    float* out        = (float*)d_out;
    const int N = in_sizes[1] / 5;

    // ws: ftR only (3 copies x GPC x 64B = 3,625,344 B)
    const size_t need = (size_t)3 * GPC * 64;
    const int use_t = (ws_size >= need) ? 1 : 0;
    unsigned int* ftR = (unsigned int*)d_ws;

    if (use_t) {
        prep_kernel<<<(NPIX + 2 + 1023) / 1024, 1024, 0, stream>>>(ft, ftR);
    }
    main_kernel<<<(N + RPB - 1) / RPB, 256, 0, stream>>>(rois, ftR, ft, out, N, use_t);
}